// Round 7
// baseline (246.385 us; speedup 1.0000x reference)
//
#include <hip/hip_runtime.h>
#include <hip/hip_bf16.h>
#include <stdint.h>

#define BATCH 2
#define S_LEN 2048
#define EMB   1024
#define NHEAD 16
#define HDIM  64

typedef __attribute__((ext_vector_type(8)))  __bf16 bf16x8;
typedef __attribute__((ext_vector_type(4)))  __bf16 bf16x4;
typedef __attribute__((ext_vector_type(4)))  float  f32x4;
typedef __attribute__((ext_vector_type(16))) float  f32x16;

#define ZERO16 ((f32x16){0.f,0.f,0.f,0.f,0.f,0.f,0.f,0.f,0.f,0.f,0.f,0.f,0.f,0.f,0.f,0.f})
#define SM_SCALE_LOG2 0.18033688011112042f  /* 0.125 * log2(e) */

static __device__ __forceinline__ void gload_lds16(const void* g, void* l) {
    __builtin_amdgcn_global_load_lds(
        (__attribute__((address_space(1))) void*)g,
        (__attribute__((address_space(3))) void*)l,
        16, 0, 0);
}

// ---------------------------------------------------------------------------
// fp32 -> bf16 conversions
// ---------------------------------------------------------------------------
__global__ void f2b_kernel(const float* __restrict__ s, __bf16* __restrict__ d, int n4) {
    int i = blockIdx.x * blockDim.x + threadIdx.x;
    if (i >= n4) return;
    float4 v = reinterpret_cast<const float4*>(s)[i];
    bf16x4 o = { (__bf16)v.x, (__bf16)v.y, (__bf16)v.z, (__bf16)v.w };
    reinterpret_cast<bf16x4*>(d)[i] = o;
}

__global__ void f2b4_kernel(const float* __restrict__ s0, const float* __restrict__ s1,
                            const float* __restrict__ s2, const float* __restrict__ s3,
                            __bf16* __restrict__ d0, __bf16* __restrict__ d1,
                            __bf16* __restrict__ d2, __bf16* __restrict__ d3, int n4) {
    int i = blockIdx.x * blockDim.x + threadIdx.x;
    if (i >= n4) return;
    const float* s = blockIdx.y == 0 ? s0 : blockIdx.y == 1 ? s1 : blockIdx.y == 2 ? s2 : s3;
    __bf16*      d = blockIdx.y == 0 ? d0 : blockIdx.y == 1 ? d1 : blockIdx.y == 2 ? d2 : d3;
    float4 v = reinterpret_cast<const float4*>(s)[i];
    bf16x4 o = { (__bf16)v.x, (__bf16)v.y, (__bf16)v.z, (__bf16)v.w };
    reinterpret_cast<bf16x4*>(d)[i] = o;
}

// ---------------------------------------------------------------------------
// 128x64-tile NT GEMM, fp32 output (final projection). Grid (N/64, M/128).
// ---------------------------------------------------------------------------
__global__ __launch_bounds__(256)
void gemm_o64(const __bf16* __restrict__ A, const __bf16* __restrict__ W,
              const float* __restrict__ bias, float* __restrict__ out,
              int M, int N, int K) {
    __shared__ __align__(16) __bf16 As[128 * 32];
    __shared__ __align__(16) __bf16 Bs[64 * 32];

    const int t    = threadIdx.x;
    const int w    = t >> 6;
    const int lane = t & 63;
    const int m0   = blockIdx.y * 128;
    const int n0   = blockIdx.x * 64;
    const int wr   = w * 32;
    const int fr   = lane & 15;
    const int kg   = (lane >> 4) * 8;

    f32x4 acc[2][4];
#pragma unroll
    for (int i = 0; i < 2; ++i)
#pragma unroll
        for (int n = 0; n < 4; ++n) acc[i][n] = (f32x4){0.f, 0.f, 0.f, 0.f};

    for (int kt = 0; kt < K; kt += 32) {
#pragma unroll
        for (int i = 0; i < 2; ++i) {
            int chunk = i * 256 + t;
            int row   = chunk >> 2;
            int col   = (chunk & 3) * 8;
            gload_lds16(A + (size_t)(m0 + row) * K + kt + col,
                        (char*)As + i * 4096 + w * 1024);
        }
        {
            int row = t >> 2;
            int col = (t & 3) * 8;
            gload_lds16(W + (size_t)(n0 + row) * K + kt + col,
                        (char*)Bs + w * 1024);
        }
        __syncthreads();

        bf16x8 af[2], bfv[4];
#pragma unroll
        for (int m = 0; m < 2; ++m)
            af[m] = *(const bf16x8*)&As[(wr + m * 16 + fr) * 32 + kg];
#pragma unroll
        for (int n = 0; n < 4; ++n)
            bfv[n] = *(const bf16x8*)&Bs[(n * 16 + fr) * 32 + kg];
#pragma unroll
        for (int m = 0; m < 2; ++m)
#pragma unroll
            for (int n = 0; n < 4; ++n)
                acc[m][n] = __builtin_amdgcn_mfma_f32_16x16x32_bf16(
                    af[m], bfv[n], acc[m][n], 0, 0, 0);
        __syncthreads();
    }

    const int rbase = (lane >> 4) * 4;
#pragma unroll
    for (int m = 0; m < 2; ++m) {
#pragma unroll
        for (int n = 0; n < 4; ++n) {
            int col  = n0 + n * 16 + fr;
            float bv = bias[col];
#pragma unroll
            for (int jj = 0; jj < 4; ++jj) {
                int row = m0 + wr + m * 16 + rbase + jj;
                out[(size_t)row * N + col] = acc[m][n][jj] + bv;
            }
        }
    }
}

// ---------------------------------------------------------------------------
// Fused QKV projection: 128x128 tiles, grid x = 24 (which*8 + nblk), y = 32.
// ---------------------------------------------------------------------------
__global__ __launch_bounds__(256)
void gemm_qkv(const __bf16* __restrict__ A,
              const __bf16* __restrict__ W0p, const __bf16* __restrict__ W1p,
              const __bf16* __restrict__ W2p,
              const float* __restrict__ b0p, const float* __restrict__ b1p,
              const float* __restrict__ b2p,
              __bf16* __restrict__ o0, __bf16* __restrict__ o1,
              __bf16* __restrict__ o2, int M, int N, int K) {
    __shared__ __align__(16) __bf16 As[128 * 32];
    __shared__ __align__(16) __bf16 Bs[128 * 32];

    const int which = blockIdx.x >> 3;
    const __bf16* W    = which == 0 ? W0p : which == 1 ? W1p : W2p;
    const float*  bias = which == 0 ? b0p : which == 1 ? b1p : b2p;
    __bf16*       out  = which == 0 ? o0  : which == 1 ? o1  : o2;

    const int t    = threadIdx.x;
    const int w    = t >> 6;
    const int lane = t & 63;
    const int m0   = blockIdx.y * 128;
    const int n0   = (blockIdx.x & 7) * 128;
    const int wr   = (w >> 1) * 64;
    const int wc   = (w & 1) * 64;
    const int fr   = lane & 15;
    const int kg   = (lane >> 4) * 8;

    f32x4 acc[4][4];
#pragma unroll
    for (int i = 0; i < 4; ++i)
#pragma unroll
        for (int j = 0; j < 4; ++j) acc[i][j] = (f32x4){0.f, 0.f, 0.f, 0.f};

    for (int kt = 0; kt < K; kt += 32) {
#pragma unroll
        for (int i = 0; i < 2; ++i) {
            int chunk = i * 256 + t;
            int row   = chunk >> 2;
            int col   = (chunk & 3) * 8;
            gload_lds16(A + (size_t)(m0 + row) * K + kt + col,
                        (char*)As + i * 4096 + w * 1024);
            gload_lds16(W + (size_t)(n0 + row) * K + kt + col,
                        (char*)Bs + i * 4096 + w * 1024);
        }
        __syncthreads();

        bf16x8 af[4], bfv[4];
#pragma unroll
        for (int m = 0; m < 4; ++m)
            af[m] = *(const bf16x8*)&As[(wr + m * 16 + fr) * 32 + kg];
#pragma unroll
        for (int n = 0; n < 4; ++n)
            bfv[n] = *(const bf16x8*)&Bs[(wc + n * 16 + fr) * 32 + kg];
#pragma unroll
        for (int m = 0; m < 4; ++m)
#pragma unroll
            for (int n = 0; n < 4; ++n)
                acc[m][n] = __builtin_amdgcn_mfma_f32_16x16x32_bf16(
                    af[m], bfv[n], acc[m][n], 0, 0, 0);
        __syncthreads();
    }

    const int rbase = (lane >> 4) * 4;
#pragma unroll
    for (int m = 0; m < 4; ++m) {
#pragma unroll
        for (int n = 0; n < 4; ++n) {
            int col  = n0 + wc + n * 16 + fr;
            float bv = bias[col];
#pragma unroll
            for (int jj = 0; jj < 4; ++jj) {
                int row = m0 + wr + m * 16 + rbase + jj;
                float v = acc[m][n][jj] + bv;
                int b = row >> 11, s = row & (S_LEN - 1);
                int hh = col >> 6, d = col & (HDIM - 1);
                out[(((size_t)(b * NHEAD + hh)) * S_LEN + s) * HDIM + d] = (__bf16)v;
            }
        }
    }
}

// ---------------------------------------------------------------------------
// Block-causal flash attention, split-KV 8-wave, paired-sub-block ILP.
// Grid (x=bh 32, y=16); qt remap pairs (qt, 15-qt) on each CU (uniform work:
// all 512 blocks co-resident at 2 blocks/CU). Wave w: q-block 4qt+(w&3),
// kv-half h2=w>>2. Per 128-key chunk: K AND V double-buffered (one barrier
// per chunk); wave computes its 64-key half as ONE paired pass: 8 interleaved
// QK MFMAs (2 indep chains) -> joint softmax (one tree/rescale over 32 regs)
// -> 8 PV MFMAs. permlane32_swap P-exchange, cvt_pk packing, defer-max,
// exp2-FMA, setprio on MFMA clusters.
// ---------------------------------------------------------------------------
#define PV_STEP(Lx, Hx, klbase)                                              \
  _Pragma("unroll")                                                          \
  for (int s2 = 0; s2 < 2; ++s2) {                                           \
    unsigned a0 = Lx[2 * s2], b0 = Lx[2 * s2 + 1];                           \
    unsigned a1 = Hx[2 * s2], b1 = Hx[2 * s2 + 1];                           \
    asm("v_permlane32_swap_b32 %0, %1" : "+v"(a0), "+v"(b0));                \
    asm("v_permlane32_swap_b32 %0, %1" : "+v"(a1), "+v"(b1));                \
    unsigned wvw[4] = { a0, a1, b0, b1 };                                    \
    bf16x8 pa = *(bf16x8*)wvw;                                               \
    const int klb = (klbase) + 16 * s2;                                      \
    {                                                                        \
      int d = q32;                                                           \
      int xx = (d ^ (d >> 3)) & 15;                                          \
      bf16x8 vf = *(const bf16x8*)&Vt[cur][d * 128 + ((klb + 8 * h) ^ (xx << 3))]; \
      oacc0 = __builtin_amdgcn_mfma_f32_32x32x16_bf16(pa, vf, oacc0, 0, 0, 0);     \
    }                                                                        \
    {                                                                        \
      int d = 32 + q32;                                                      \
      int xx = (d ^ (d >> 3)) & 15;                                          \
      bf16x8 vf = *(const bf16x8*)&Vt[cur][d * 128 + ((klb + 8 * h) ^ (xx << 3))]; \
      oacc1 = __builtin_amdgcn_mfma_f32_32x32x16_bf16(pa, vf, oacc1, 0, 0, 0);     \
    }                                                                        \
  }

#define RESCALE_CHECK(pmaxv)                                                 \
  if (__any((pmaxv) > mrun + 8.f)) {                                         \
    float mnew = fmaxf(mrun, (pmaxv));                                       \
    float fac  = exp2f(mrun - mnew);                                         \
    mrun = mnew;                                                             \
    lrun *= fac;                                                             \
    bc[w8][q32] = fac;                                                       \
    asm volatile("s_waitcnt lgkmcnt(0)" ::: "memory");                       \
    __builtin_amdgcn_sched_barrier(0);                                       \
    _Pragma("unroll")                                                        \
    for (int q2 = 0; q2 < 4; ++q2) {                                         \
      f32x4 fv = *(const f32x4*)&bc[w8][8 * q2 + 4 * h];                     \
      _Pragma("unroll")                                                      \
      for (int jj = 0; jj < 4; ++jj) {                                       \
        oacc0[4 * q2 + jj] *= fv[jj];                                        \
        oacc1[4 * q2 + jj] *= fv[jj];                                        \
      }                                                                      \
    }                                                                        \
  }

__global__ __launch_bounds__(512, 4)
void attn5_kernel(const __bf16* __restrict__ Q, const __bf16* __restrict__ Kv,
                  const __bf16* __restrict__ V, __bf16* __restrict__ out) {
    __shared__ __align__(16) __bf16 Kt[2][128 * 64];   // 32 KB
    __shared__ __align__(16) __bf16 Vt[2][64 * 128];   // 32 KB
    __shared__ float bc[8][32];                        // 1 KB

    const int t    = threadIdx.x;
    const int w8   = t >> 6;
    const int lane = t & 63;
    const int h    = lane >> 5;
    const int q32  = lane & 31;
    const int j    = w8 & 3;
    const int h2   = w8 >> 2;
    const int bh   = blockIdx.x;   // 0..31
    const int yy   = blockIdx.y;   // 0..15
    const int qt   = (yy < 8) ? (15 - yy) : (yy - 8);   // pairs (15-y, y) per CU
    const int qb   = 4 * qt + j;

    const __bf16* Qp = Q  + (size_t)bh * S_LEN * HDIM;
    const __bf16* Kp = Kv + (size_t)bh * S_LEN * HDIM;
    const __bf16* Vp = V  + (size_t)bh * S_LEN * HDIM;

    const int qrow = qb * 32 + q32;

    bf16x8 qreg[4];
#pragma unroll
    for (int ks = 0; ks < 4; ++ks)
        qreg[ks] = *(const bf16x8*)&Qp[(size_t)qrow * HDIM + 16 * ks + 8 * h];

    f32x16 oacc0 = ZERO16, oacc1 = ZERO16;
    float mrun = -1e30f, lrun = 0.f;

    // ---- prologue: stage chunk 0 into buffer 0 ----
    {
#pragma unroll
        for (int i = 0; i < 2; ++i) {
            int c16 = i * 512 + t;
            int key = c16 >> 3;
            int d0  = ((c16 & 7) ^ (key & 7)) * 8;
            gload_lds16(Kp + (size_t)key * HDIM + d0, (char*)&Kt[0][0] + c16 * 16);
        }
        bf16x8 vr[2];
#pragma unroll
        for (int i = 0; i < 2; ++i)
            vr[i] = *(const bf16x8*)&Vp[(size_t)(64 * h2 + lane) * HDIM + (4 * i + j) * 8];
        const int key = 64 * h2 + lane;
#pragma unroll
        for (int i = 0; i < 2; ++i) {
            int d0 = (4 * i + j) * 8;
#pragma unroll
            for (int e = 0; e < 8; ++e) {
                int d = d0 + e;
                int x = (d ^ (d >> 3)) & 15;
                Vt[0][d * 128 + (key ^ (x << 3))] = vr[i][e];
            }
        }
        __syncthreads();
    }

    for (int c = 0; c <= qt; ++c) {
        const int  cur = c & 1;
        const bool pre = (c < qt);
        bf16x8 vr[2];
        if (pre) {
            const int kb = (c + 1) * 128;
#pragma unroll
            for (int i = 0; i < 2; ++i) {
                int c16 = i * 512 + t;
                int key = c16 >> 3;
                int d0  = ((c16 & 7) ^ (key & 7)) * 8;
                gload_lds16(Kp + (size_t)(kb + key) * HDIM + d0,
                            (char*)&Kt[cur ^ 1][0] + c16 * 16);
            }
#pragma unroll
            for (int i = 0; i < 2; ++i)
                vr[i] = *(const bf16x8*)&Vp[(size_t)(kb + 64 * h2 + lane) * HDIM +
                                            (4 * i + j) * 8];
        }

        // causal sub-block count for this wave in this chunk
        const int ns = pre ? 2 : (h2 ? (j == 3 ? 2 : (j == 2 ? 1 : 0))
                                     : (j == 0 ? 1 : 2));
        const int kl0 = 64 * h2;
        const int kl1 = 64 * h2 + 32;

        if (ns == 2) {
            // ---- paired QK^T: two independent MFMA chains ----
            f32x16 sa0 = ZERO16, sa1 = ZERO16;
            __builtin_amdgcn_s_setprio(1);
#pragma unroll
            for (int ks = 0; ks < 4; ++ks) {
                const int swz = (16 * ks + 8 * h) ^ ((q32 & 7) << 3);
                bf16x8 kf0 = *(const bf16x8*)&Kt[cur][(kl0 + q32) * 64 + swz];
                bf16x8 kf1 = *(const bf16x8*)&Kt[cur][(kl1 + q32) * 64 + swz];
                sa0 = __builtin_amdgcn_mfma_f32_32x32x16_bf16(kf0, qreg[ks], sa0, 0, 0, 0);
                sa1 = __builtin_amdgcn_mfma_f32_32x32x16_bf16(kf1, qreg[ks], sa1, 0, 0, 0);
            }
            __builtin_amdgcn_s_setprio(0);

            // ---- joint softmax over 32 regs ----
            float rmax = fmaxf(sa0[0], sa1[0]);
#pragma unroll
            for (int r = 1; r < 16; ++r) rmax = fmaxf(rmax, fmaxf(sa0[r], sa1[r]));
            float pmax = rmax * SM_SCALE_LOG2;
            pmax = fmaxf(pmax, __shfl_xor(pmax, 32));
            RESCALE_CHECK(pmax);

            float ps = 0.f;
#pragma unroll
            for (int r = 0; r < 16; ++r) {
                float p0 = exp2f(__builtin_fmaf(sa0[r], SM_SCALE_LOG2, -mrun));
                float p1 = exp2f(__builtin_fmaf(sa1[r], SM_SCALE_LOG2, -mrun));
                ps += p0 + p1;
                sa0[r] = p0;
                sa1[r] = p1;
            }
            ps += __shfl_xor(ps, 32);
            lrun += ps;

            unsigned L0[4], H0[4], L1[4], H1[4];
#pragma unroll
            for (int g = 0; g < 4; ++g) {
                asm("v_cvt_pk_bf16_f32 %0, %1, %2"
                    : "=v"(L0[g]) : "v"(sa0[4 * g]), "v"(sa0[4 * g + 1]));
                asm("v_cvt_pk_bf16_f32 %0, %1, %2"
                    : "=v"(H0[g]) : "v"(sa0[4 * g + 2]), "v"(sa0[4 * g + 3]));
                asm("v_cvt_pk_bf16_f32 %0, %1, %2"
                    : "=v"(L1[g]) : "v"(sa1[4 * g]), "v"(sa1[4 * g + 1]));
                asm("v_cvt_pk_bf16_f32 %0, %1, %2"
                    : "=v"(H1[g]) : "v"(sa1[4 * g + 2]), "v"(sa1[4 * g + 3]));
            }

            __builtin_amdgcn_s_setprio(1);
            PV_STEP(L0, H0, kl0);
            PV_STEP(L1, H1, kl1);
            __builtin_amdgcn_s_setprio(0);
        } else if (ns == 1) {
            // ---- single sub-block (causal tail) ----
            f32x16 sac = ZERO16;
            __builtin_amdgcn_s_setprio(1);
#pragma unroll
            for (int ks = 0; ks < 4; ++ks) {
                const int swz = (16 * ks + 8 * h) ^ ((q32 & 7) << 3);
                bf16x8 kf = *(const bf16x8*)&Kt[cur][(kl0 + q32) * 64 + swz];
                sac = __builtin_amdgcn_mfma_f32_32x32x16_bf16(kf, qreg[ks], sac, 0, 0, 0);
            }
            __builtin_amdgcn_s_setprio(0);

            float rmax = sac[0];
#pragma unroll
            for (int r = 1; r < 16; ++r) rmax = fmaxf(rmax, sac[r]);
            float pmax = rmax * SM_SCALE_LOG2;
            pmax = fmaxf(pmax, __shfl_xor(pmax, 32));
            RESCALE_CHECK(pmax);

            float ps = 0.f;
#pragma unroll
            for (int r = 0; r < 16; ++r) {
                float pv = exp2f(__builtin_fmaf(sac[r], SM_SCALE_LOG2, -mrun));
                ps += pv;
                sac[r] = pv;
            }
            ps += __shfl_xor(ps, 32);
            lrun += ps;

            unsigned L[4], H[4];
#pragma unroll
            for (int g = 0; g < 4; ++g) {
                asm("v_cvt_pk_bf16_f32 %0, %1, %2"
                    : "=v"(L[g]) : "v"(sac[4 * g]), "v"(sac[4 * g + 1]));
                asm("v_cvt_pk_bf16_f32 %0, %1, %2"
                    : "=v"(H[g]) : "v"(sac[4 * g + 2]), "v"(sac[4 * g + 3]));
            }

            __builtin_amdgcn_s_setprio(1);
            PV_STEP(L, H, kl0);
            __builtin_amdgcn_s_setprio(0);
        }

        if (pre) {
            // write next V tile (other buffer; no conflict with cur readers)
            const int buf = cur ^ 1;
            const int key = 64 * h2 + lane;
#pragma unroll
            for (int i = 0; i < 2; ++i) {
                int d0 = (4 * i + j) * 8;
#pragma unroll
                for (int e = 0; e < 8; ++e) {
                    int d = d0 + e;
                    int x = (d ^ (d >> 3)) & 15;
                    Vt[buf][d * 128 + (key ^ (x << 3))] = vr[i][e];
                }
            }
        }
        __syncthreads();   // K[cur^1] (vmcnt drained) + V[cur^1] ready
    }

    // ---- pair merge: waves (j, h2=0) <- (j, h2=1) ----
    float* MLm = (float*)&Vt[0][0];      // [8][32]
    float* MLl = MLm + 256;              // [8][32]
    float* Oex = (float*)&Kt[0][0];      // [4][32][64] f32 = 32 KB

    if (h == 0) { MLm[w8 * 32 + q32] = mrun; MLl[w8 * 32 + q32] = lrun; }
    if (h2 == 1) {
        float* ob = Oex + j * 2048;
#pragma unroll
        for (int q2 = 0; q2 < 4; ++q2)
#pragma unroll
            for (int jj = 0; jj < 4; ++jj) {
                int r  = 4 * q2 + jj;
                int rl = 8 * q2 + 4 * h + jj;
                ob[rl * 64 + q32]      = oacc0[r];
                ob[rl * 64 + 32 + q32] = oacc1[r];
            }
    }
    __syncthreads();

    if (h2 == 0) {
        const int b = bh >> 4, hh = bh & (NHEAD - 1);
        __bf16* op = out + (size_t)b * S_LEN * EMB + hh * HDIM;
        const float* ob = Oex + j * 2048;
#pragma unroll
        for (int q2 = 0; q2 < 4; ++q2) {
            f32x4 ma4 = *(const f32x4*)&MLm[j * 32 + 8 * q2 + 4 * h];
            f32x4 mb4 = *(const f32x4*)&MLm[(j + 4) * 32 + 8 * q2 + 4 * h];
            f32x4 la4 = *(const f32x4*)&MLl[j * 32 + 8 * q2 + 4 * h];
            f32x4 lb4 = *(const f32x4*)&MLl[(j + 4) * 32 + 8 * q2 + 4 * h];
#pragma unroll
            for (int jj = 0; jj < 4; ++jj) {
                float ma = ma4[jj], mb = mb4[jj];
                float mst = fmaxf(ma, mb);
                float sa  = exp2f(ma - mst), sb = exp2f(mb - mst);
                float inv = 1.f / (la4[jj] * sa + lb4[jj] * sb);
                int r  = 4 * q2 + jj;
                int rl = 8 * q2 + 4 * h + jj;
                int row = qb * 32 + rl;
                float v0 = (oacc0[r] * sa + ob[rl * 64 + q32] * sb) * inv;
                float v1 = (oacc1[r] * sa + ob[rl * 64 + 32 + q32] * sb) * inv;
                op[(size_t)row * EMB + q32]      = (__bf16)v0;
                op[(size_t)row * EMB + 32 + q32] = (__bf16)v1;
            }
        }
    }
}

// ---------------------------------------------------------------------------
extern "C" void kernel_launch(void* const* d_in, const int* in_sizes, int n_in,
                              void* d_out, int out_size, void* d_ws, size_t ws_size,
                              hipStream_t stream) {
    const float* x  = (const float*)d_in[0];
    const float* Wq = (const float*)d_in[1];
    const float* bq = (const float*)d_in[2];
    const float* Wk = (const float*)d_in[3];
    const float* bk = (const float*)d_in[4];
    const float* Wv = (const float*)d_in[5];
    const float* bv = (const float*)d_in[6];
    const float* Wo = (const float*)d_in[7];
    const float* bo = (const float*)d_in[8];
    float* out = (float*)d_out;

    char* ws = (char*)d_ws;
    __bf16* xb  = (__bf16*)(ws + 0);
    __bf16* wqb = (__bf16*)(ws + 8388608);
    __bf16* wkb = (__bf16*)(ws + 10485760);
    __bf16* wvb = (__bf16*)(ws + 12582912);
    __bf16* wob = (__bf16*)(ws + 14680064);
    __bf16* Qb  = (__bf16*)(ws + 16777216);
    __bf16* Kb  = (__bf16*)(ws + 25165824);
    __bf16* Vb  = (__bf16*)(ws + 33554432);
    __bf16* Ab  = (__bf16*)(ws + 41943040);

    const int M = BATCH * S_LEN;  // 4096
    const int N = EMB;            // 1024
    const int K = EMB;            // 1024

    f2b_kernel<<<(M * K / 4 + 255) / 256, 256, 0, stream>>>(x, xb, M * K / 4);
    f2b4_kernel<<<dim3(N * K / 4 / 256, 4), 256, 0, stream>>>(
        Wq, Wk, Wv, Wo, wqb, wkb, wvb, wob, N * K / 4);

    gemm_qkv<<<dim3(24, M / 128), 256, 0, stream>>>(
        xb, wqb, wkb, wvb, bq, bk, bv, Qb, Kb, Vb, M, N, K);

    attn5_kernel<<<dim3(BATCH * NHEAD, S_LEN / 128), 512, 0, stream>>>(Qb, Kb, Vb, Ab);

    gemm_o64<<<dim3(16, M / 128), 256, 0, stream>>>(Ab, wob, bo, out, M, N, K);
}

// Round 8
// 134.318 us; speedup vs baseline: 1.8343x; 1.8343x over previous
//
#include <hip/hip_runtime.h>
#include <hip/hip_bf16.h>
#include <stdint.h>

#define BATCH 2
#define S_LEN 2048
#define EMB   1024
#define NHEAD 16
#define HDIM  64

typedef __attribute__((ext_vector_type(8)))  __bf16 bf16x8;
typedef __attribute__((ext_vector_type(4)))  __bf16 bf16x4;
typedef __attribute__((ext_vector_type(4)))  float  f32x4;
typedef __attribute__((ext_vector_type(16))) float  f32x16;

#define ZERO16 ((f32x16){0.f,0.f,0.f,0.f,0.f,0.f,0.f,0.f,0.f,0.f,0.f,0.f,0.f,0.f,0.f,0.f})
#define SM_SCALE_LOG2 0.18033688011112042f  /* 0.125 * log2(e) */

static __device__ __forceinline__ void gload_lds16(const void* g, void* l) {
    __builtin_amdgcn_global_load_lds(
        (__attribute__((address_space(1))) void*)g,
        (__attribute__((address_space(3))) void*)l,
        16, 0, 0);
}

// ---------------------------------------------------------------------------
// fp32 -> bf16 conversions
// ---------------------------------------------------------------------------
__global__ void f2b_kernel(const float* __restrict__ s, __bf16* __restrict__ d, int n4) {
    int i = blockIdx.x * blockDim.x + threadIdx.x;
    if (i >= n4) return;
    float4 v = reinterpret_cast<const float4*>(s)[i];
    bf16x4 o = { (__bf16)v.x, (__bf16)v.y, (__bf16)v.z, (__bf16)v.w };
    reinterpret_cast<bf16x4*>(d)[i] = o;
}

__global__ void f2b4_kernel(const float* __restrict__ s0, const float* __restrict__ s1,
                            const float* __restrict__ s2, const float* __restrict__ s3,
                            __bf16* __restrict__ d0, __bf16* __restrict__ d1,
                            __bf16* __restrict__ d2, __bf16* __restrict__ d3, int n4) {
    int i = blockIdx.x * blockDim.x + threadIdx.x;
    if (i >= n4) return;
    const float* s = blockIdx.y == 0 ? s0 : blockIdx.y == 1 ? s1 : blockIdx.y == 2 ? s2 : s3;
    __bf16*      d = blockIdx.y == 0 ? d0 : blockIdx.y == 1 ? d1 : blockIdx.y == 2 ? d2 : d3;
    float4 v = reinterpret_cast<const float4*>(s)[i];
    bf16x4 o = { (__bf16)v.x, (__bf16)v.y, (__bf16)v.z, (__bf16)v.w };
    reinterpret_cast<bf16x4*>(d)[i] = o;
}

// ---------------------------------------------------------------------------
// 128x128 NT GEMM, fp32 output (final projection). Grid (N/128, M/128).
// ---------------------------------------------------------------------------
__global__ __launch_bounds__(256)
void gemm_out(const __bf16* __restrict__ A, const __bf16* __restrict__ W,
              const float* __restrict__ bias, float* __restrict__ out,
              int M, int N, int K) {
    __shared__ __align__(16) __bf16 As[128 * 32];
    __shared__ __align__(16) __bf16 Bs[128 * 32];

    const int t    = threadIdx.x;
    const int w    = t >> 6;
    const int lane = t & 63;
    const int m0   = blockIdx.y * 128;
    const int n0   = blockIdx.x * 128;
    const int wr   = (w >> 1) * 64;
    const int wc   = (w & 1) * 64;
    const int fr   = lane & 15;
    const int kg   = (lane >> 4) * 8;

    f32x4 acc[4][4];
#pragma unroll
    for (int i = 0; i < 4; ++i)
#pragma unroll
        for (int j = 0; j < 4; ++j) acc[i][j] = (f32x4){0.f, 0.f, 0.f, 0.f};

    for (int kt = 0; kt < K; kt += 32) {
#pragma unroll
        for (int i = 0; i < 2; ++i) {
            int chunk = i * 256 + t;
            int row   = chunk >> 2;
            int col   = (chunk & 3) * 8;
            gload_lds16(A + (size_t)(m0 + row) * K + kt + col,
                        (char*)As + i * 4096 + w * 1024);
            gload_lds16(W + (size_t)(n0 + row) * K + kt + col,
                        (char*)Bs + i * 4096 + w * 1024);
        }
        __syncthreads();

        bf16x8 af[4], bfv[4];
#pragma unroll
        for (int m = 0; m < 4; ++m)
            af[m] = *(const bf16x8*)&As[(wr + m * 16 + fr) * 32 + kg];
#pragma unroll
        for (int n = 0; n < 4; ++n)
            bfv[n] = *(const bf16x8*)&Bs[(wc + n * 16 + fr) * 32 + kg];
#pragma unroll
        for (int m = 0; m < 4; ++m)
#pragma unroll
            for (int n = 0; n < 4; ++n)
                acc[m][n] = __builtin_amdgcn_mfma_f32_16x16x32_bf16(
                    af[m], bfv[n], acc[m][n], 0, 0, 0);
        __syncthreads();
    }

    const int rbase = (lane >> 4) * 4;
#pragma unroll
    for (int m = 0; m < 4; ++m) {
#pragma unroll
        for (int n = 0; n < 4; ++n) {
            int col  = n0 + wc + n * 16 + fr;
            float bv = bias[col];
#pragma unroll
            for (int jj = 0; jj < 4; ++jj) {
                int row = m0 + wr + m * 16 + rbase + jj;
                out[(size_t)row * N + col] = acc[m][n][jj] + bv;
            }
        }
    }
}

// ---------------------------------------------------------------------------
// Fused QKV projection, 128x128 tiles. Grid x = 24 (which*8 + xx), y = 32.
// which 0/1 (Q,K): C = x . W^T  -> [B,H,S,HD].
// which 2   (V) : C = Wv . x^T -> V^T [B,H,HD,S]  (lane axis = s, coalesced).
// ---------------------------------------------------------------------------
__global__ __launch_bounds__(256)
void gemm_qkv(const __bf16* __restrict__ xb,
              const __bf16* __restrict__ Wqb, const __bf16* __restrict__ Wkb,
              const __bf16* __restrict__ Wvb,
              const float* __restrict__ bqp, const float* __restrict__ bkp,
              const float* __restrict__ bvp,
              __bf16* __restrict__ Qo, __bf16* __restrict__ Ko,
              __bf16* __restrict__ VTo, int K) {
    __shared__ __align__(16) __bf16 As[128 * 32];
    __shared__ __align__(16) __bf16 Bs[128 * 32];

    const int which = blockIdx.x >> 3;
    const int xx    = blockIdx.x & 7;

    const __bf16* Ap;
    const __bf16* Wp;
    int m0, n0;
    if (which == 2) {            // V^T: A = Wv (1024 rows), W = x (4096 rows)
        Ap = Wvb; Wp = xb;
        m0 = xx * 128;           // over (h,d)
        n0 = blockIdx.y * 128;   // over (b,s)
    } else {
        Ap = xb; Wp = (which == 0) ? Wqb : Wkb;
        m0 = blockIdx.y * 128;   // over (b,s)
        n0 = xx * 128;           // over (h,d)
    }
    const float* bias = which == 0 ? bqp : which == 1 ? bkp : bvp;

    const int t    = threadIdx.x;
    const int w    = t >> 6;
    const int lane = t & 63;
    const int wr   = (w >> 1) * 64;
    const int wc   = (w & 1) * 64;
    const int fr   = lane & 15;
    const int kg   = (lane >> 4) * 8;

    f32x4 acc[4][4];
#pragma unroll
    for (int i = 0; i < 4; ++i)
#pragma unroll
        for (int j = 0; j < 4; ++j) acc[i][j] = (f32x4){0.f, 0.f, 0.f, 0.f};

    for (int kt = 0; kt < K; kt += 32) {
#pragma unroll
        for (int i = 0; i < 2; ++i) {
            int chunk = i * 256 + t;
            int row   = chunk >> 2;
            int col   = (chunk & 3) * 8;
            gload_lds16(Ap + (size_t)(m0 + row) * K + kt + col,
                        (char*)As + i * 4096 + w * 1024);
            gload_lds16(Wp + (size_t)(n0 + row) * K + kt + col,
                        (char*)Bs + i * 4096 + w * 1024);
        }
        __syncthreads();

        bf16x8 af[4], bfv[4];
#pragma unroll
        for (int m = 0; m < 4; ++m)
            af[m] = *(const bf16x8*)&As[(wr + m * 16 + fr) * 32 + kg];
#pragma unroll
        for (int n = 0; n < 4; ++n)
            bfv[n] = *(const bf16x8*)&Bs[(wc + n * 16 + fr) * 32 + kg];
#pragma unroll
        for (int m = 0; m < 4; ++m)
#pragma unroll
            for (int n = 0; n < 4; ++n)
                acc[m][n] = __builtin_amdgcn_mfma_f32_16x16x32_bf16(
                    af[m], bfv[n], acc[m][n], 0, 0, 0);
        __syncthreads();
    }

    const int rbase = (lane >> 4) * 4;
    if (which == 2) {
        // rows = (h,d), cols = (b,s); bias indexed by ROW; V^T layout [bh][d][s]
#pragma unroll
        for (int m = 0; m < 4; ++m) {
#pragma unroll
            for (int n = 0; n < 4; ++n) {
                int col = n0 + wc + n * 16 + fr;       // b*2048 + s
                int b   = col >> 11, s = col & (S_LEN - 1);
#pragma unroll
                for (int jj = 0; jj < 4; ++jj) {
                    int row = m0 + wr + m * 16 + rbase + jj;   // h*64 + d
                    int hh  = row >> 6, d = row & (HDIM - 1);
                    float v = acc[m][n][jj] + bias[row];
                    VTo[(((size_t)(b * NHEAD + hh)) * HDIM + d) * S_LEN + s] = (__bf16)v;
                }
            }
        }
    } else {
        __bf16* outp = (which == 0) ? Qo : Ko;
#pragma unroll
        for (int m = 0; m < 4; ++m) {
#pragma unroll
            for (int n = 0; n < 4; ++n) {
                int col  = n0 + wc + n * 16 + fr;
                float bv = bias[col];
#pragma unroll
                for (int jj = 0; jj < 4; ++jj) {
                    int row = m0 + wr + m * 16 + rbase + jj;
                    float v = acc[m][n][jj] + bv;
                    int b = row >> 11, s = row & (S_LEN - 1);
                    int hh = col >> 6, d = col & (HDIM - 1);
                    outp[(((size_t)(b * NHEAD + hh)) * S_LEN + s) * HDIM + d] = (__bf16)v;
                }
            }
        }
    }
}

// ---------------------------------------------------------------------------
// Block-causal flash attention: q-tile 64, 8 waves = (j in {0,1}) x (kv-quarter
// h4 in {0..3}). Grid (x=bh 32, y=32), qt = 31-y (heavy-first LPT; 1024 blocks
// -> 2/CU resident with backfill). Per 128-key chunk: K and V^T both staged by
// global_load_lds (XOR-swizzled source), double-buffered, ONE barrier/chunk.
// Wave computes ONE 32-key sub-block per chunk (index 4c+h4 <= qb). 4-way LDS
// merge at the end. Per-wave regs = r6 single-chain footprint (no V transpose).
// ---------------------------------------------------------------------------
__global__ __launch_bounds__(512, 4)
void attn6_kernel(const __bf16* __restrict__ Q, const __bf16* __restrict__ Kv,
                  const __bf16* __restrict__ VT, __bf16* __restrict__ out) {
    __shared__ __align__(16) char smem[66560];
    __bf16* Kt0 = (__bf16*)smem;                 // Kt[2][128*64] = 32 KB
    __bf16* Vt0 = (__bf16*)(smem + 32768);       // Vt[2][64*128] = 32 KB
    float*  bc  = (float*)(smem + 65536);        // [8][32] = 1 KB

    const int t    = threadIdx.x;
    const int w8   = t >> 6;
    const int lane = t & 63;
    const int h    = lane >> 5;
    const int q32  = lane & 31;
    const int j    = w8 & 1;
    const int h4   = w8 >> 1;
    const int bh   = blockIdx.x;               // 0..31
    const int qt   = 31 - blockIdx.y;          // heavy first (LPT)
    const int qb   = 2 * qt + j;               // this wave's q-block (32 rows)
    const int C    = (2 * qt + 5) >> 2;        // 128-key chunks

    const __bf16* Qp  = Q  + (size_t)bh * S_LEN * HDIM;
    const __bf16* Kp  = Kv + (size_t)bh * S_LEN * HDIM;
    const __bf16* VTp = VT + (size_t)bh * HDIM * S_LEN;

    const int qrow = qb * 32 + q32;

    bf16x8 qreg[4];
#pragma unroll
    for (int ks = 0; ks < 4; ++ks)
        qreg[ks] = *(const bf16x8*)&Qp[(size_t)qrow * HDIM + 16 * ks + 8 * h];

    f32x16 oacc0 = ZERO16, oacc1 = ZERO16;
    float mrun = -1e30f, lrun = 0.f;

    // ---- stage helper pattern (K rows swizzled by key&7; V^T rows by d&7) ----
    // prologue: chunk 0 -> buffer 0
    {
#pragma unroll
        for (int i = 0; i < 2; ++i) {
            int c16 = i * 512 + t;
            int key = c16 >> 3;
            int d0  = ((c16 & 7) ^ (key & 7)) * 8;
            gload_lds16(Kp + (size_t)key * HDIM + d0, (char*)Kt0 + c16 * 16);
        }
#pragma unroll
        for (int i = 0; i < 2; ++i) {
            int c16 = i * 512 + t;
            int d   = c16 >> 4;
            int o   = c16 & 15;
            gload_lds16(VTp + (size_t)d * S_LEN + ((o ^ (d & 7)) * 8),
                        (char*)Vt0 + c16 * 16);
        }
        __syncthreads();
    }

    for (int c = 0; c < C; ++c) {
        const int cur = c & 1;
        if (c + 1 < C) {
            const int kb = (c + 1) * 128;
#pragma unroll
            for (int i = 0; i < 2; ++i) {
                int c16 = i * 512 + t;
                int key = c16 >> 3;
                int d0  = ((c16 & 7) ^ (key & 7)) * 8;
                gload_lds16(Kp + (size_t)(kb + key) * HDIM + d0,
                            (char*)Kt0 + (cur ^ 1) * 16384 + c16 * 16);
            }
#pragma unroll
            for (int i = 0; i < 2; ++i) {
                int c16 = i * 512 + t;
                int d   = c16 >> 4;
                int o   = c16 & 15;
                gload_lds16(VTp + (size_t)d * S_LEN + kb + ((o ^ (d & 7)) * 8),
                            (char*)Vt0 + (cur ^ 1) * 16384 + c16 * 16);
            }
        }

        if (4 * c + h4 <= qb) {
            const __bf16* Ktc = Kt0 + cur * 8192;   // 16384 B
            const __bf16* Vtc = Vt0 + cur * 8192;
            const int klocal = 32 * h4;

            // S^T = K . Q^T
            f32x16 sac = ZERO16;
            __builtin_amdgcn_s_setprio(1);
#pragma unroll
            for (int ks = 0; ks < 4; ++ks) {
                bf16x8 kf = *(const bf16x8*)&Ktc[(klocal + q32) * 64 +
                                ((16 * ks + 8 * h) ^ ((q32 & 7) << 3))];
                sac = __builtin_amdgcn_mfma_f32_32x32x16_bf16(kf, qreg[ks], sac, 0, 0, 0);
            }
            __builtin_amdgcn_s_setprio(0);

            float rmax = sac[0];
#pragma unroll
            for (int r = 1; r < 16; ++r) rmax = fmaxf(rmax, sac[r]);
            float pmax = rmax * SM_SCALE_LOG2;
            pmax = fmaxf(pmax, __shfl_xor(pmax, 32));

            if (__any(pmax > mrun + 8.f)) {
                float mnew = fmaxf(mrun, pmax);
                float fac  = exp2f(mrun - mnew);
                mrun = mnew;
                lrun *= fac;
                bc[w8 * 32 + q32] = fac;
                asm volatile("s_waitcnt lgkmcnt(0)" ::: "memory");
                __builtin_amdgcn_sched_barrier(0);
#pragma unroll
                for (int q2 = 0; q2 < 4; ++q2) {
                    f32x4 fv = *(const f32x4*)&bc[w8 * 32 + 8 * q2 + 4 * h];
#pragma unroll
                    for (int jj = 0; jj < 4; ++jj) {
                        oacc0[4 * q2 + jj] *= fv[jj];
                        oacc1[4 * q2 + jj] *= fv[jj];
                    }
                }
            }

            float ps = 0.f;
#pragma unroll
            for (int r = 0; r < 16; ++r) {
                float pv = exp2f(__builtin_fmaf(sac[r], SM_SCALE_LOG2, -mrun));
                ps += pv;
                sac[r] = pv;
            }
            ps += __shfl_xor(ps, 32);
            lrun += ps;

            unsigned L[4], H[4];
#pragma unroll
            for (int g = 0; g < 4; ++g) {
                asm("v_cvt_pk_bf16_f32 %0, %1, %2"
                    : "=v"(L[g]) : "v"(sac[4 * g]), "v"(sac[4 * g + 1]));
                asm("v_cvt_pk_bf16_f32 %0, %1, %2"
                    : "=v"(H[g]) : "v"(sac[4 * g + 2]), "v"(sac[4 * g + 3]));
            }

            __builtin_amdgcn_s_setprio(1);
#pragma unroll
            for (int s2 = 0; s2 < 2; ++s2) {
                unsigned a0 = L[2 * s2], b0 = L[2 * s2 + 1];
                unsigned a1 = H[2 * s2], b1 = H[2 * s2 + 1];
                asm("v_permlane32_swap_b32 %0, %1" : "+v"(a0), "+v"(b0));
                asm("v_permlane32_swap_b32 %0, %1" : "+v"(a1), "+v"(b1));
                unsigned wvw[4] = { a0, a1, b0, b1 };
                bf16x8 pa = *(bf16x8*)wvw;

                const int klb = klocal + 16 * s2 + 8 * h;
#pragma unroll
                for (int n = 0; n < 2; ++n) {
                    int d = 32 * n + q32;
                    bf16x8 vf = *(const bf16x8*)&Vtc[d * 128 +
                                    (klb ^ ((d & 7) << 3))];
                    if (n == 0)
                        oacc0 = __builtin_amdgcn_mfma_f32_32x32x16_bf16(pa, vf, oacc0, 0, 0, 0);
                    else
                        oacc1 = __builtin_amdgcn_mfma_f32_32x32x16_bf16(pa, vf, oacc1, 0, 0, 0);
                }
            }
            __builtin_amdgcn_s_setprio(0);
        }

        __syncthreads();   // drains vmcnt: next buffers ready; cur reads done
    }

    // ---- 4-way merge: wave (j,0) <- waves (j,1..3) ----
    float* Oex = (float*)smem;                   // 6 slots x 8 KB = 48 KB
    float* MLm = (float*)(smem + 49152);         // [8][32]
    float* MLl = (float*)(smem + 50176);         // [8][32]

    if (h == 0) { MLm[w8 * 32 + q32] = mrun; MLl[w8 * 32 + q32] = lrun; }
    if (h4 != 0) {
        float* ob = Oex + (j * 3 + h4 - 1) * 2048;
#pragma unroll
        for (int q2 = 0; q2 < 4; ++q2)
#pragma unroll
            for (int jj = 0; jj < 4; ++jj) {
                int r  = 4 * q2 + jj;
                int rl = 8 * q2 + 4 * h + jj;
                ob[rl * 64 + q32]      = oacc0[r];
                ob[rl * 64 + 32 + q32] = oacc1[r];
            }
    }
    __syncthreads();

    if (h4 == 0) {
        const int b = bh >> 4, hh = bh & (NHEAD - 1);
        __bf16* op = out + (size_t)b * S_LEN * EMB + hh * HDIM;
        const float* ob1 = Oex + (j * 3 + 0) * 2048;
        const float* ob2 = Oex + (j * 3 + 1) * 2048;
        const float* ob3 = Oex + (j * 3 + 2) * 2048;
#pragma unroll
        for (int q2 = 0; q2 < 4; ++q2) {
            f32x4 mv[4], lv[4];
#pragma unroll
            for (int p = 0; p < 4; ++p) {
                int wp = (p << 1) | j;
                mv[p] = *(const f32x4*)&MLm[wp * 32 + 8 * q2 + 4 * h];
                lv[p] = *(const f32x4*)&MLl[wp * 32 + 8 * q2 + 4 * h];
            }
#pragma unroll
            for (int jj = 0; jj < 4; ++jj) {
                float mst = fmaxf(fmaxf(mv[0][jj], mv[1][jj]),
                                  fmaxf(mv[2][jj], mv[3][jj]));
                float s0 = exp2f(mv[0][jj] - mst);
                float s1 = exp2f(mv[1][jj] - mst);
                float s2 = exp2f(mv[2][jj] - mst);
                float s3 = exp2f(mv[3][jj] - mst);
                float inv = 1.f / (lv[0][jj] * s0 + lv[1][jj] * s1 +
                                   lv[2][jj] * s2 + lv[3][jj] * s3);
                int r  = 4 * q2 + jj;
                int rl = 8 * q2 + 4 * h + jj;
                int row = qb * 32 + rl;
                float v0 = (oacc0[r] * s0 + ob1[rl * 64 + q32] * s1 +
                            ob2[rl * 64 + q32] * s2 + ob3[rl * 64 + q32] * s3) * inv;
                float v1 = (oacc1[r] * s0 + ob1[rl * 64 + 32 + q32] * s1 +
                            ob2[rl * 64 + 32 + q32] * s2 + ob3[rl * 64 + 32 + q32] * s3) * inv;
                op[(size_t)row * EMB + q32]      = (__bf16)v0;
                op[(size_t)row * EMB + 32 + q32] = (__bf16)v1;
            }
        }
    }
}

// ---------------------------------------------------------------------------
extern "C" void kernel_launch(void* const* d_in, const int* in_sizes, int n_in,
                              void* d_out, int out_size, void* d_ws, size_t ws_size,
                              hipStream_t stream) {
    const float* x  = (const float*)d_in[0];
    const float* Wq = (const float*)d_in[1];
    const float* bq = (const float*)d_in[2];
    const float* Wk = (const float*)d_in[3];
    const float* bk = (const float*)d_in[4];
    const float* Wv = (const float*)d_in[5];
    const float* bv = (const float*)d_in[6];
    const float* Wo = (const float*)d_in[7];
    const float* bo = (const float*)d_in[8];
    float* out = (float*)d_out;

    char* ws = (char*)d_ws;
    __bf16* xb  = (__bf16*)(ws + 0);
    __bf16* wqb = (__bf16*)(ws + 8388608);
    __bf16* wkb = (__bf16*)(ws + 10485760);
    __bf16* wvb = (__bf16*)(ws + 12582912);
    __bf16* wob = (__bf16*)(ws + 14680064);
    __bf16* Qb  = (__bf16*)(ws + 16777216);
    __bf16* Kb  = (__bf16*)(ws + 25165824);
    __bf16* VTb = (__bf16*)(ws + 33554432);   // [B,H,HD,S] bf16
    __bf16* Ab  = (__bf16*)(ws + 41943040);

    const int M = BATCH * S_LEN;  // 4096
    const int N = EMB;            // 1024
    const int K = EMB;            // 1024

    f2b_kernel<<<(M * K / 4 + 255) / 256, 256, 0, stream>>>(x, xb, M * K / 4);
    f2b4_kernel<<<dim3(N * K / 4 / 256, 4), 256, 0, stream>>>(
        Wq, Wk, Wv, Wo, wqb, wkb, wvb, wob, N * K / 4);

    gemm_qkv<<<dim3(24, 32), 256, 0, stream>>>(
        xb, wqb, wkb, wvb, bq, bk, bv, Qb, Kb, VTb, K);

    attn6_kernel<<<dim3(BATCH * NHEAD, 32), 512, 0, stream>>>(Qb, Kb, VTb, Ab);

    gemm_out<<<dim3(N / 128, M / 128), 256, 0, stream>>>(Ab, wob, bo, out, M, N, K);
}

// Round 9
// 123.640 us; speedup vs baseline: 1.9928x; 1.0864x over previous
//
#include <hip/hip_runtime.h>
#include <hip/hip_bf16.h>
#include <stdint.h>

#define BATCH 2
#define S_LEN 2048
#define EMB   1024
#define NHEAD 16
#define HDIM  64

typedef __attribute__((ext_vector_type(8)))  __bf16 bf16x8;
typedef __attribute__((ext_vector_type(4)))  __bf16 bf16x4;
typedef __attribute__((ext_vector_type(4)))  float  f32x4;
typedef __attribute__((ext_vector_type(16))) float  f32x16;

#define ZERO16 ((f32x16){0.f,0.f,0.f,0.f,0.f,0.f,0.f,0.f,0.f,0.f,0.f,0.f,0.f,0.f,0.f,0.f})
#define SM_SCALE_LOG2 0.18033688011112042f  /* 0.125 * log2(e) */

static __device__ __forceinline__ void gload_lds16(const void* g, void* l) {
    __builtin_amdgcn_global_load_lds(
        (__attribute__((address_space(1))) void*)g,
        (__attribute__((address_space(3))) void*)l,
        16, 0, 0);
}

// ---------------------------------------------------------------------------
// Fused fp32 -> bf16 conversion: x (1M float4) + 4 weights (256K float4 each)
// ---------------------------------------------------------------------------
__global__ void f2b_all(const float* __restrict__ x,
                        const float* __restrict__ Wq, const float* __restrict__ Wk,
                        const float* __restrict__ Wv, const float* __restrict__ Wo,
                        __bf16* __restrict__ xb,
                        __bf16* __restrict__ wqb, __bf16* __restrict__ wkb,
                        __bf16* __restrict__ wvb, __bf16* __restrict__ wob) {
    int i = blockIdx.x * blockDim.x + threadIdx.x;   // 0 .. 2097151
    const float* s;
    __bf16* d;
    int off;
    if (i < (1 << 20)) {
        s = x; d = xb; off = i;
    } else {
        int r   = i - (1 << 20);
        int seg = r >> 18;
        off = r & ((1 << 18) - 1);
        s = seg == 0 ? Wq : seg == 1 ? Wk : seg == 2 ? Wv : Wo;
        d = seg == 0 ? wqb : seg == 1 ? wkb : seg == 2 ? wvb : wob;
    }
    float4 v = reinterpret_cast<const float4*>(s)[off];
    bf16x4 o = { (__bf16)v.x, (__bf16)v.y, (__bf16)v.z, (__bf16)v.w };
    reinterpret_cast<bf16x4*>(d)[off] = o;
}

// ---------------------------------------------------------------------------
// 128x64-tile NT GEMM, fp32 out (final projection). Grid (N/64, M/128) = 512.
// Double-buffered LDS, T3-minimum 2-phase: stage(k+1) -> compute(k) -> barrier.
// ---------------------------------------------------------------------------
__global__ __launch_bounds__(256)
void gemm_o64(const __bf16* __restrict__ A, const __bf16* __restrict__ W,
              const float* __restrict__ bias, float* __restrict__ out,
              int M, int N, int K) {
    __shared__ __align__(16) __bf16 As[2][128 * 32];   // 16 KB
    __shared__ __align__(16) __bf16 Bs[2][64 * 32];    //  8 KB

    const int t    = threadIdx.x;
    const int w    = t >> 6;
    const int lane = t & 63;
    const int m0   = blockIdx.y * 128;
    const int n0   = blockIdx.x * 64;
    const int wr   = w * 32;
    const int fr   = lane & 15;
    const int kg   = (lane >> 4) * 8;

    f32x4 acc[2][4];
#pragma unroll
    for (int i = 0; i < 2; ++i)
#pragma unroll
        for (int n = 0; n < 4; ++n) acc[i][n] = (f32x4){0.f, 0.f, 0.f, 0.f};

    auto stage = [&](int kt, int buf) {
#pragma unroll
        for (int i = 0; i < 2; ++i) {
            int chunk = i * 256 + t;
            int row   = chunk >> 2;
            int col   = (chunk & 3) * 8;
            gload_lds16(A + (size_t)(m0 + row) * K + kt + col,
                        (char*)&As[buf][0] + i * 4096 + w * 1024);
        }
        {
            int row = t >> 2;
            int col = (t & 3) * 8;
            gload_lds16(W + (size_t)(n0 + row) * K + kt + col,
                        (char*)&Bs[buf][0] + w * 1024);
        }
    };

    stage(0, 0);
    __syncthreads();

    const int NK = K / 32;
    for (int k6 = 0; k6 < NK; ++k6) {
        const int cur = k6 & 1;
        if (k6 + 1 < NK) stage((k6 + 1) * 32, cur ^ 1);

        bf16x8 af[2], bfv[4];
#pragma unroll
        for (int m = 0; m < 2; ++m)
            af[m] = *(const bf16x8*)&As[cur][(wr + m * 16 + fr) * 32 + kg];
#pragma unroll
        for (int n = 0; n < 4; ++n)
            bfv[n] = *(const bf16x8*)&Bs[cur][(n * 16 + fr) * 32 + kg];
#pragma unroll
        for (int m = 0; m < 2; ++m)
#pragma unroll
            for (int n = 0; n < 4; ++n)
                acc[m][n] = __builtin_amdgcn_mfma_f32_16x16x32_bf16(
                    af[m], bfv[n], acc[m][n], 0, 0, 0);
        __syncthreads();   // drains vmcnt: buf^1 staged; cur reads done
    }

    const int rbase = (lane >> 4) * 4;
#pragma unroll
    for (int m = 0; m < 2; ++m) {
#pragma unroll
        for (int n = 0; n < 4; ++n) {
            int col  = n0 + n * 16 + fr;
            float bv = bias[col];
#pragma unroll
            for (int jj = 0; jj < 4; ++jj) {
                int row = m0 + wr + m * 16 + rbase + jj;
                out[(size_t)row * N + col] = acc[m][n][jj] + bv;
            }
        }
    }
}

// ---------------------------------------------------------------------------
// Fused QKV projection, 128x128 tiles, double-buffered 2-phase K-loop.
// Grid x = 24 (which*8 + xx), y = 32.
// which 0/1 (Q,K): C = x . W^T  -> [B,H,S,HD].
// which 2   (V) : C = Wv . x^T -> V^T [B,H,HD,S]  (lane axis = s, coalesced).
// ---------------------------------------------------------------------------
__global__ __launch_bounds__(256)
void gemm_qkv(const __bf16* __restrict__ xb,
              const __bf16* __restrict__ Wqb, const __bf16* __restrict__ Wkb,
              const __bf16* __restrict__ Wvb,
              const float* __restrict__ bqp, const float* __restrict__ bkp,
              const float* __restrict__ bvp,
              __bf16* __restrict__ Qo, __bf16* __restrict__ Ko,
              __bf16* __restrict__ VTo, int K) {
    __shared__ __align__(16) __bf16 As[2][128 * 32];   // 16 KB
    __shared__ __align__(16) __bf16 Bs[2][128 * 32];   // 16 KB

    const int which = blockIdx.x >> 3;
    const int xx    = blockIdx.x & 7;

    const __bf16* Ap;
    const __bf16* Wp;
    int m0, n0;
    if (which == 2) {            // V^T: A = Wv (1024 rows), W = x (4096 rows)
        Ap = Wvb; Wp = xb;
        m0 = xx * 128;           // over (h,d)
        n0 = blockIdx.y * 128;   // over (b,s)
    } else {
        Ap = xb; Wp = (which == 0) ? Wqb : Wkb;
        m0 = blockIdx.y * 128;   // over (b,s)
        n0 = xx * 128;           // over (h,d)
    }
    const float* bias = which == 0 ? bqp : which == 1 ? bkp : bvp;

    const int t    = threadIdx.x;
    const int w    = t >> 6;
    const int lane = t & 63;
    const int wr   = (w >> 1) * 64;
    const int wc   = (w & 1) * 64;
    const int fr   = lane & 15;
    const int kg   = (lane >> 4) * 8;

    f32x4 acc[4][4];
#pragma unroll
    for (int i = 0; i < 4; ++i)
#pragma unroll
        for (int j = 0; j < 4; ++j) acc[i][j] = (f32x4){0.f, 0.f, 0.f, 0.f};

    auto stage = [&](int kt, int buf) {
#pragma unroll
        for (int i = 0; i < 2; ++i) {
            int chunk = i * 256 + t;
            int row   = chunk >> 2;
            int col   = (chunk & 3) * 8;
            gload_lds16(Ap + (size_t)(m0 + row) * K + kt + col,
                        (char*)&As[buf][0] + i * 4096 + w * 1024);
            gload_lds16(Wp + (size_t)(n0 + row) * K + kt + col,
                        (char*)&Bs[buf][0] + i * 4096 + w * 1024);
        }
    };

    stage(0, 0);
    __syncthreads();

    const int NK = K / 32;
    for (int k6 = 0; k6 < NK; ++k6) {
        const int cur = k6 & 1;
        if (k6 + 1 < NK) stage((k6 + 1) * 32, cur ^ 1);

        bf16x8 af[4], bfv[4];
#pragma unroll
        for (int m = 0; m < 4; ++m)
            af[m] = *(const bf16x8*)&As[cur][(wr + m * 16 + fr) * 32 + kg];
#pragma unroll
        for (int n = 0; n < 4; ++n)
            bfv[n] = *(const bf16x8*)&Bs[cur][(wc + n * 16 + fr) * 32 + kg];
#pragma unroll
        for (int m = 0; m < 4; ++m)
#pragma unroll
            for (int n = 0; n < 4; ++n)
                acc[m][n] = __builtin_amdgcn_mfma_f32_16x16x32_bf16(
                    af[m], bfv[n], acc[m][n], 0, 0, 0);
        __syncthreads();   // drains vmcnt: buf^1 staged; cur reads done
    }

    const int rbase = (lane >> 4) * 4;
    if (which == 2) {
        // rows = (h,d), cols = (b,s); bias indexed by ROW; V^T layout [bh][d][s]
#pragma unroll
        for (int m = 0; m < 4; ++m) {
#pragma unroll
            for (int n = 0; n < 4; ++n) {
                int col = n0 + wc + n * 16 + fr;       // b*2048 + s
                int b   = col >> 11, s = col & (S_LEN - 1);
#pragma unroll
                for (int jj = 0; jj < 4; ++jj) {
                    int row = m0 + wr + m * 16 + rbase + jj;   // h*64 + d
                    int hh  = row >> 6, d = row & (HDIM - 1);
                    float v = acc[m][n][jj] + bias[row];
                    VTo[(((size_t)(b * NHEAD + hh)) * HDIM + d) * S_LEN + s] = (__bf16)v;
                }
            }
        }
    } else {
        __bf16* outp = (which == 0) ? Qo : Ko;
#pragma unroll
        for (int m = 0; m < 4; ++m) {
#pragma unroll
            for (int n = 0; n < 4; ++n) {
                int col  = n0 + wc + n * 16 + fr;
                float bv = bias[col];
#pragma unroll
                for (int jj = 0; jj < 4; ++jj) {
                    int row = m0 + wr + m * 16 + rbase + jj;
                    float v = acc[m][n][jj] + bv;
                    int b = row >> 11, s = row & (S_LEN - 1);
                    int hh = col >> 6, d = col & (HDIM - 1);
                    outp[(((size_t)(b * NHEAD + hh)) * S_LEN + s) * HDIM + d] = (__bf16)v;
                }
            }
        }
    }
}

// ---------------------------------------------------------------------------
// Block-causal flash attention: q-tile 64, 8 waves = (j in {0,1}) x (kv-quarter
// h4 in {0..3}). Grid (x=bh 32, y=32), qt = 31-y (heavy-first LPT; 1024 blocks
// -> 2/CU resident with backfill). Per 128-key chunk: K and V^T both staged by
// global_load_lds (XOR-swizzled source), double-buffered, ONE barrier/chunk.
// Wave computes ONE 32-key sub-block per chunk (index 4c+h4 <= qb). 4-way LDS
// merge at the end.
// ---------------------------------------------------------------------------
__global__ __launch_bounds__(512, 4)
void attn6_kernel(const __bf16* __restrict__ Q, const __bf16* __restrict__ Kv,
                  const __bf16* __restrict__ VT, __bf16* __restrict__ out) {
    __shared__ __align__(16) char smem[66560];
    __bf16* Kt0 = (__bf16*)smem;                 // Kt[2][128*64] = 32 KB
    __bf16* Vt0 = (__bf16*)(smem + 32768);       // Vt[2][64*128] = 32 KB
    float*  bc  = (float*)(smem + 65536);        // [8][32] = 1 KB

    const int t    = threadIdx.x;
    const int w8   = t >> 6;
    const int lane = t & 63;
    const int h    = lane >> 5;
    const int q32  = lane & 31;
    const int j    = w8 & 1;
    const int h4   = w8 >> 1;
    const int bh   = blockIdx.x;               // 0..31
    const int qt   = 31 - blockIdx.y;          // heavy first (LPT)
    const int qb   = 2 * qt + j;               // this wave's q-block (32 rows)
    const int C    = (2 * qt + 5) >> 2;        // 128-key chunks

    const __bf16* Qp  = Q  + (size_t)bh * S_LEN * HDIM;
    const __bf16* Kp  = Kv + (size_t)bh * S_LEN * HDIM;
    const __bf16* VTp = VT + (size_t)bh * HDIM * S_LEN;

    const int qrow = qb * 32 + q32;

    bf16x8 qreg[4];
#pragma unroll
    for (int ks = 0; ks < 4; ++ks)
        qreg[ks] = *(const bf16x8*)&Qp[(size_t)qrow * HDIM + 16 * ks + 8 * h];

    f32x16 oacc0 = ZERO16, oacc1 = ZERO16;
    float mrun = -1e30f, lrun = 0.f;

    // prologue: chunk 0 -> buffer 0
    {
#pragma unroll
        for (int i = 0; i < 2; ++i) {
            int c16 = i * 512 + t;
            int key = c16 >> 3;
            int d0  = ((c16 & 7) ^ (key & 7)) * 8;
            gload_lds16(Kp + (size_t)key * HDIM + d0, (char*)Kt0 + c16 * 16);
        }
#pragma unroll
        for (int i = 0; i < 2; ++i) {
            int c16 = i * 512 + t;
            int d   = c16 >> 4;
            int o   = c16 & 15;
            gload_lds16(VTp + (size_t)d * S_LEN + ((o ^ (d & 7)) * 8),
                        (char*)Vt0 + c16 * 16);
        }
        __syncthreads();
    }

    for (int c = 0; c < C; ++c) {
        const int cur = c & 1;
        if (c + 1 < C) {
            const int kb = (c + 1) * 128;
#pragma unroll
            for (int i = 0; i < 2; ++i) {
                int c16 = i * 512 + t;
                int key = c16 >> 3;
                int d0  = ((c16 & 7) ^ (key & 7)) * 8;
                gload_lds16(Kp + (size_t)(kb + key) * HDIM + d0,
                            (char*)Kt0 + (cur ^ 1) * 16384 + c16 * 16);
            }
#pragma unroll
            for (int i = 0; i < 2; ++i) {
                int c16 = i * 512 + t;
                int d   = c16 >> 4;
                int o   = c16 & 15;
                gload_lds16(VTp + (size_t)d * S_LEN + kb + ((o ^ (d & 7)) * 8),
                            (char*)Vt0 + (cur ^ 1) * 16384 + c16 * 16);
            }
        }

        if (4 * c + h4 <= qb) {
            const __bf16* Ktc = Kt0 + cur * 8192;
            const __bf16* Vtc = Vt0 + cur * 8192;
            const int klocal = 32 * h4;

            // S^T = K . Q^T
            f32x16 sac = ZERO16;
            __builtin_amdgcn_s_setprio(1);
#pragma unroll
            for (int ks = 0; ks < 4; ++ks) {
                bf16x8 kf = *(const bf16x8*)&Ktc[(klocal + q32) * 64 +
                                ((16 * ks + 8 * h) ^ ((q32 & 7) << 3))];
                sac = __builtin_amdgcn_mfma_f32_32x32x16_bf16(kf, qreg[ks], sac, 0, 0, 0);
            }
            __builtin_amdgcn_s_setprio(0);

            float rmax = sac[0];
#pragma unroll
            for (int r = 1; r < 16; ++r) rmax = fmaxf(rmax, sac[r]);
            float pmax = rmax * SM_SCALE_LOG2;
            pmax = fmaxf(pmax, __shfl_xor(pmax, 32));

            if (__any(pmax > mrun + 8.f)) {
                float mnew = fmaxf(mrun, pmax);
                float fac  = exp2f(mrun - mnew);
                mrun = mnew;
                lrun *= fac;
                bc[w8 * 32 + q32] = fac;
                asm volatile("s_waitcnt lgkmcnt(0)" ::: "memory");
                __builtin_amdgcn_sched_barrier(0);
#pragma unroll
                for (int q2 = 0; q2 < 4; ++q2) {
                    f32x4 fv = *(const f32x4*)&bc[w8 * 32 + 8 * q2 + 4 * h];
#pragma unroll
                    for (int jj = 0; jj < 4; ++jj) {
                        oacc0[4 * q2 + jj] *= fv[jj];
                        oacc1[4 * q2 + jj] *= fv[jj];
                    }
                }
            }

            float ps = 0.f;
#pragma unroll
            for (int r = 0; r < 16; ++r) {
                float pv = exp2f(__builtin_fmaf(sac[r], SM_SCALE_LOG2, -mrun));
                ps += pv;
                sac[r] = pv;
            }
            ps += __shfl_xor(ps, 32);
            lrun += ps;

            unsigned L[4], H[4];
#pragma unroll
            for (int g = 0; g < 4; ++g) {
                asm("v_cvt_pk_bf16_f32 %0, %1, %2"
                    : "=v"(L[g]) : "v"(sac[4 * g]), "v"(sac[4 * g + 1]));
                asm("v_cvt_pk_bf16_f32 %0, %1, %2"
                    : "=v"(H[g]) : "v"(sac[4 * g + 2]), "v"(sac[4 * g + 3]));
            }

            __builtin_amdgcn_s_setprio(1);
#pragma unroll
            for (int s2 = 0; s2 < 2; ++s2) {
                unsigned a0 = L[2 * s2], b0 = L[2 * s2 + 1];
                unsigned a1 = H[2 * s2], b1 = H[2 * s2 + 1];
                asm("v_permlane32_swap_b32 %0, %1" : "+v"(a0), "+v"(b0));
                asm("v_permlane32_swap_b32 %0, %1" : "+v"(a1), "+v"(b1));
                unsigned wvw[4] = { a0, a1, b0, b1 };
                bf16x8 pa = *(bf16x8*)wvw;

                const int klb = klocal + 16 * s2 + 8 * h;
#pragma unroll
                for (int n = 0; n < 2; ++n) {
                    int d = 32 * n + q32;
                    bf16x8 vf = *(const bf16x8*)&Vtc[d * 128 +
                                    (klb ^ ((d & 7) << 3))];
                    if (n == 0)
                        oacc0 = __builtin_amdgcn_mfma_f32_32x32x16_bf16(pa, vf, oacc0, 0, 0, 0);
                    else
                        oacc1 = __builtin_amdgcn_mfma_f32_32x32x16_bf16(pa, vf, oacc1, 0, 0, 0);
                }
            }
            __builtin_amdgcn_s_setprio(0);
        }

        __syncthreads();   // drains vmcnt: next buffers ready; cur reads done
    }

    // ---- 4-way merge: wave (j,0) <- waves (j,1..3) ----
    float* Oex = (float*)smem;                   // 6 slots x 8 KB = 48 KB
    float* MLm = (float*)(smem + 49152);         // [8][32]
    float* MLl = (float*)(smem + 50176);         // [8][32]

    if (h == 0) { MLm[w8 * 32 + q32] = mrun; MLl[w8 * 32 + q32] = lrun; }
    if (h4 != 0) {
        float* ob = Oex + (j * 3 + h4 - 1) * 2048;
#pragma unroll
        for (int q2 = 0; q2 < 4; ++q2)
#pragma unroll
            for (int jj = 0; jj < 4; ++jj) {
                int r  = 4 * q2 + jj;
                int rl = 8 * q2 + 4 * h + jj;
                ob[rl * 64 + q32]      = oacc0[r];
                ob[rl * 64 + 32 + q32] = oacc1[r];
            }
    }
    __syncthreads();

    if (h4 == 0) {
        const int b = bh >> 4, hh = bh & (NHEAD - 1);
        __bf16* op = out + (size_t)b * S_LEN * EMB + hh * HDIM;
        const float* ob1 = Oex + (j * 3 + 0) * 2048;
        const float* ob2 = Oex + (j * 3 + 1) * 2048;
        const float* ob3 = Oex + (j * 3 + 2) * 2048;
#pragma unroll
        for (int q2 = 0; q2 < 4; ++q2) {
            f32x4 mv[4], lv[4];
#pragma unroll
            for (int p = 0; p < 4; ++p) {
                int wp = (p << 1) | j;
                mv[p] = *(const f32x4*)&MLm[wp * 32 + 8 * q2 + 4 * h];
                lv[p] = *(const f32x4*)&MLl[wp * 32 + 8 * q2 + 4 * h];
            }
#pragma unroll
            for (int jj = 0; jj < 4; ++jj) {
                float mst = fmaxf(fmaxf(mv[0][jj], mv[1][jj]),
                                  fmaxf(mv[2][jj], mv[3][jj]));
                float s0 = exp2f(mv[0][jj] - mst);
                float s1 = exp2f(mv[1][jj] - mst);
                float s2 = exp2f(mv[2][jj] - mst);
                float s3 = exp2f(mv[3][jj] - mst);
                float inv = 1.f / (lv[0][jj] * s0 + lv[1][jj] * s1 +
                                   lv[2][jj] * s2 + lv[3][jj] * s3);
                int r  = 4 * q2 + jj;
                int rl = 8 * q2 + 4 * h + jj;
                int row = qb * 32 + rl;
                float v0 = (oacc0[r] * s0 + ob1[rl * 64 + q32] * s1 +
                            ob2[rl * 64 + q32] * s2 + ob3[rl * 64 + q32] * s3) * inv;
                float v1 = (oacc1[r] * s0 + ob1[rl * 64 + 32 + q32] * s1 +
                            ob2[rl * 64 + 32 + q32] * s2 + ob3[rl * 64 + 32 + q32] * s3) * inv;
                op[(size_t)row * EMB + q32]      = (__bf16)v0;
                op[(size_t)row * EMB + 32 + q32] = (__bf16)v1;
            }
        }
    }
}

// ---------------------------------------------------------------------------
extern "C" void kernel_launch(void* const* d_in, const int* in_sizes, int n_in,
                              void* d_out, int out_size, void* d_ws, size_t ws_size,
                              hipStream_t stream) {
    const float* x  = (const float*)d_in[0];
    const float* Wq = (const float*)d_in[1];
    const float* bq = (const float*)d_in[2];
    const float* Wk = (const float*)d_in[3];
    const float* bk = (const float*)d_in[4];
    const float* Wv = (const float*)d_in[5];
    const float* bv = (const float*)d_in[6];
    const float* Wo = (const float*)d_in[7];
    const float* bo = (const float*)d_in[8];
    float* out = (float*)d_out;

    char* ws = (char*)d_ws;
    __bf16* xb  = (__bf16*)(ws + 0);
    __bf16* wqb = (__bf16*)(ws + 8388608);
    __bf16* wkb = (__bf16*)(ws + 10485760);
    __bf16* wvb = (__bf16*)(ws + 12582912);
    __bf16* wob = (__bf16*)(ws + 14680064);
    __bf16* Qb  = (__bf16*)(ws + 16777216);
    __bf16* Kb  = (__bf16*)(ws + 25165824);
    __bf16* VTb = (__bf16*)(ws + 33554432);   // [B,H,HD,S] bf16
    __bf16* Ab  = (__bf16*)(ws + 41943040);

    const int M = BATCH * S_LEN;  // 4096
    const int N = EMB;            // 1024
    const int K = EMB;            // 1024

    f2b_all<<<8192, 256, 0, stream>>>(x, Wq, Wk, Wv, Wo, xb, wqb, wkb, wvb, wob);

    gemm_qkv<<<dim3(24, 32), 256, 0, stream>>>(
        xb, wqb, wkb, wvb, bq, bk, bv, Qb, Kb, VTb, K);

    attn6_kernel<<<dim3(BATCH * NHEAD, 32), 512, 0, stream>>>(Qb, Kb, VTb, Ab);

    gemm_o64<<<dim3(16, M / 128), 256, 0, stream>>>(Ab, wob, bo, out, M, N, K);
}

// Round 10
// 123.230 us; speedup vs baseline: 1.9994x; 1.0033x over previous
//
#include <hip/hip_runtime.h>
#include <hip/hip_bf16.h>
#include <stdint.h>

#define BATCH 2
#define S_LEN 2048
#define EMB   1024
#define NHEAD 16
#define HDIM  64

typedef __attribute__((ext_vector_type(8)))  __bf16 bf16x8;
typedef __attribute__((ext_vector_type(4)))  __bf16 bf16x4;
typedef __attribute__((ext_vector_type(4)))  float  f32x4;
typedef __attribute__((ext_vector_type(16))) float  f32x16;

#define ZERO16 ((f32x16){0.f,0.f,0.f,0.f,0.f,0.f,0.f,0.f,0.f,0.f,0.f,0.f,0.f,0.f,0.f,0.f})
#define SM_SCALE_LOG2 0.18033688011112042f  /* 0.125 * log2(e) */

static __device__ __forceinline__ void gload_lds16(const void* g, void* l) {
    __builtin_amdgcn_global_load_lds(
        (__attribute__((address_space(1))) void*)g,
        (__attribute__((address_space(3))) void*)l,
        16, 0, 0);
}

// ---------------------------------------------------------------------------
// Fused fp32 -> bf16 conversion: x (1M float4) + 4 weights (256K float4 each)
// ---------------------------------------------------------------------------
__global__ void f2b_all(const float* __restrict__ x,
                        const float* __restrict__ Wq, const float* __restrict__ Wk,
                        const float* __restrict__ Wv, const float* __restrict__ Wo,
                        __bf16* __restrict__ xb,
                        __bf16* __restrict__ wqb, __bf16* __restrict__ wkb,
                        __bf16* __restrict__ wvb, __bf16* __restrict__ wob) {
    int i = blockIdx.x * blockDim.x + threadIdx.x;   // 0 .. 2097151
    const float* s;
    __bf16* d;
    int off;
    if (i < (1 << 20)) {
        s = x; d = xb; off = i;
    } else {
        int r   = i - (1 << 20);
        int seg = r >> 18;
        off = r & ((1 << 18) - 1);
        s = seg == 0 ? Wq : seg == 1 ? Wk : seg == 2 ? Wv : Wo;
        d = seg == 0 ? wqb : seg == 1 ? wkb : seg == 2 ? wvb : wob;
    }
    float4 v = reinterpret_cast<const float4*>(s)[off];
    bf16x4 o = { (__bf16)v.x, (__bf16)v.y, (__bf16)v.z, (__bf16)v.w };
    reinterpret_cast<bf16x4*>(d)[off] = o;
}

// ---------------------------------------------------------------------------
// 128x64-tile NT GEMM, fp32 out (final projection). Grid (N/64, M/128) = 512.
// Double-buffered LDS, 2-phase: stage(k+1) -> compute(k) -> barrier.
// ---------------------------------------------------------------------------
__global__ __launch_bounds__(256)
void gemm_o64(const __bf16* __restrict__ A, const __bf16* __restrict__ W,
              const float* __restrict__ bias, float* __restrict__ out,
              int M, int N, int K) {
    __shared__ __align__(16) __bf16 As[2][128 * 32];   // 16 KB
    __shared__ __align__(16) __bf16 Bs[2][64 * 32];    //  8 KB

    const int t    = threadIdx.x;
    const int w    = t >> 6;
    const int lane = t & 63;
    const int m0   = blockIdx.y * 128;
    const int n0   = blockIdx.x * 64;
    const int wr   = w * 32;
    const int fr   = lane & 15;
    const int kg   = (lane >> 4) * 8;

    f32x4 acc[2][4];
#pragma unroll
    for (int i = 0; i < 2; ++i)
#pragma unroll
        for (int n = 0; n < 4; ++n) acc[i][n] = (f32x4){0.f, 0.f, 0.f, 0.f};

    auto stage = [&](int kt, int buf) {
#pragma unroll
        for (int i = 0; i < 2; ++i) {
            int chunk = i * 256 + t;
            int row   = chunk >> 2;
            int col   = (chunk & 3) * 8;
            gload_lds16(A + (size_t)(m0 + row) * K + kt + col,
                        (char*)&As[buf][0] + i * 4096 + w * 1024);
        }
        {
            int row = t >> 2;
            int col = (t & 3) * 8;
            gload_lds16(W + (size_t)(n0 + row) * K + kt + col,
                        (char*)&Bs[buf][0] + w * 1024);
        }
    };

    stage(0, 0);
    __syncthreads();

    const int NK = K / 32;
    for (int k6 = 0; k6 < NK; ++k6) {
        const int cur = k6 & 1;
        if (k6 + 1 < NK) stage((k6 + 1) * 32, cur ^ 1);

        bf16x8 af[2], bfv[4];
#pragma unroll
        for (int m = 0; m < 2; ++m)
            af[m] = *(const bf16x8*)&As[cur][(wr + m * 16 + fr) * 32 + kg];
#pragma unroll
        for (int n = 0; n < 4; ++n)
            bfv[n] = *(const bf16x8*)&Bs[cur][(n * 16 + fr) * 32 + kg];
#pragma unroll
        for (int m = 0; m < 2; ++m)
#pragma unroll
            for (int n = 0; n < 4; ++n)
                acc[m][n] = __builtin_amdgcn_mfma_f32_16x16x32_bf16(
                    af[m], bfv[n], acc[m][n], 0, 0, 0);
        __syncthreads();
    }

    const int rbase = (lane >> 4) * 4;
#pragma unroll
    for (int m = 0; m < 2; ++m) {
#pragma unroll
        for (int n = 0; n < 4; ++n) {
            int col  = n0 + n * 16 + fr;
            float bv = bias[col];
#pragma unroll
            for (int jj = 0; jj < 4; ++jj) {
                int row = m0 + wr + m * 16 + rbase + jj;
                out[(size_t)row * N + col] = acc[m][n][jj] + bv;
            }
        }
    }
}

// ---------------------------------------------------------------------------
// Fused QKV projection, 128x128 tiles, double-buffered 2-phase K-loop.
// Grid x = 24 (which*8 + xx), y = 32.
// which 0/1 (Q,K): C = x . W^T  -> [B,H,S,HD].
// which 2   (V) : C = Wv . x^T -> V^T [B,H,HD,S]  (lane axis = s, coalesced).
// ---------------------------------------------------------------------------
__global__ __launch_bounds__(256)
void gemm_qkv(const __bf16* __restrict__ xb,
              const __bf16* __restrict__ Wqb, const __bf16* __restrict__ Wkb,
              const __bf16* __restrict__ Wvb,
              const float* __restrict__ bqp, const float* __restrict__ bkp,
              const float* __restrict__ bvp,
              __bf16* __restrict__ Qo, __bf16* __restrict__ Ko,
              __bf16* __restrict__ VTo, int K) {
    __shared__ __align__(16) __bf16 As[2][128 * 32];   // 16 KB
    __shared__ __align__(16) __bf16 Bs[2][128 * 32];   // 16 KB

    const int which = blockIdx.x >> 3;
    const int xx    = blockIdx.x & 7;

    const __bf16* Ap;
    const __bf16* Wp;
    int m0, n0;
    if (which == 2) {            // V^T: A = Wv (1024 rows), W = x (4096 rows)
        Ap = Wvb; Wp = xb;
        m0 = xx * 128;           // over (h,d)
        n0 = blockIdx.y * 128;   // over (b,s)
    } else {
        Ap = xb; Wp = (which == 0) ? Wqb : Wkb;
        m0 = blockIdx.y * 128;   // over (b,s)
        n0 = xx * 128;           // over (h,d)
    }
    const float* bias = which == 0 ? bqp : which == 1 ? bkp : bvp;

    const int t    = threadIdx.x;
    const int w    = t >> 6;
    const int lane = t & 63;
    const int wr   = (w >> 1) * 64;
    const int wc   = (w & 1) * 64;
    const int fr   = lane & 15;
    const int kg   = (lane >> 4) * 8;

    f32x4 acc[4][4];
#pragma unroll
    for (int i = 0; i < 4; ++i)
#pragma unroll
        for (int j = 0; j < 4; ++j) acc[i][j] = (f32x4){0.f, 0.f, 0.f, 0.f};

    auto stage = [&](int kt, int buf) {
#pragma unroll
        for (int i = 0; i < 2; ++i) {
            int chunk = i * 256 + t;
            int row   = chunk >> 2;
            int col   = (chunk & 3) * 8;
            gload_lds16(Ap + (size_t)(m0 + row) * K + kt + col,
                        (char*)&As[buf][0] + i * 4096 + w * 1024);
            gload_lds16(Wp + (size_t)(n0 + row) * K + kt + col,
                        (char*)&Bs[buf][0] + i * 4096 + w * 1024);
        }
    };

    stage(0, 0);
    __syncthreads();

    const int NK = K / 32;
    for (int k6 = 0; k6 < NK; ++k6) {
        const int cur = k6 & 1;
        if (k6 + 1 < NK) stage((k6 + 1) * 32, cur ^ 1);

        bf16x8 af[4], bfv[4];
#pragma unroll
        for (int m = 0; m < 4; ++m)
            af[m] = *(const bf16x8*)&As[cur][(wr + m * 16 + fr) * 32 + kg];
#pragma unroll
        for (int n = 0; n < 4; ++n)
            bfv[n] = *(const bf16x8*)&Bs[cur][(wc + n * 16 + fr) * 32 + kg];
#pragma unroll
        for (int m = 0; m < 4; ++m)
#pragma unroll
            for (int n = 0; n < 4; ++n)
                acc[m][n] = __builtin_amdgcn_mfma_f32_16x16x32_bf16(
                    af[m], bfv[n], acc[m][n], 0, 0, 0);
        __syncthreads();
    }

    const int rbase = (lane >> 4) * 4;
    if (which == 2) {
#pragma unroll
        for (int m = 0; m < 4; ++m) {
#pragma unroll
            for (int n = 0; n < 4; ++n) {
                int col = n0 + wc + n * 16 + fr;       // b*2048 + s
                int b   = col >> 11, s = col & (S_LEN - 1);
#pragma unroll
                for (int jj = 0; jj < 4; ++jj) {
                    int row = m0 + wr + m * 16 + rbase + jj;   // h*64 + d
                    int hh  = row >> 6, d = row & (HDIM - 1);
                    float v = acc[m][n][jj] + bias[row];
                    VTo[(((size_t)(b * NHEAD + hh)) * HDIM + d) * S_LEN + s] = (__bf16)v;
                }
            }
        }
    } else {
        __bf16* outp = (which == 0) ? Qo : Ko;
#pragma unroll
        for (int m = 0; m < 4; ++m) {
#pragma unroll
            for (int n = 0; n < 4; ++n) {
                int col  = n0 + wc + n * 16 + fr;
                float bv = bias[col];
#pragma unroll
                for (int jj = 0; jj < 4; ++jj) {
                    int row = m0 + wr + m * 16 + rbase + jj;
                    float v = acc[m][n][jj] + bv;
                    int b = row >> 11, s = row & (S_LEN - 1);
                    int hh = col >> 6, d = col & (HDIM - 1);
                    outp[(((size_t)(b * NHEAD + hh)) * S_LEN + s) * HDIM + d] = (__bf16)v;
                }
            }
        }
    }
}

// ---------------------------------------------------------------------------
// Block-causal flash attention: q-tile 64, 8 waves = (j in {0,1}) x (kv-quarter
// h4 in {0..3}). Grid (x=bh 32, y=32), qt = 31-y (heavy-first LPT; 1024 blocks).
// LDS 50 KB -> 3 blocks/CU (24 waves/CU = 6/SIMD). Per 128-key chunk:
//   issue V_c -> Vt (single buffer; consumed late, latency hides under QK)
//   issue K_{c+1} -> Kt[cur^1] (double buffer; consumed first next chunk)
//   QK/softmax from Kt[cur] -> barrier (V ready) -> PV from Vt -> barrier.
// Wave computes ONE 32-key sub-block per chunk (index 4c+h4 <= qb). 4-way LDS
// merge at the end.
// ---------------------------------------------------------------------------
__global__ __launch_bounds__(512, 4)
void attn7_kernel(const __bf16* __restrict__ Q, const __bf16* __restrict__ Kv,
                  const __bf16* __restrict__ VT, __bf16* __restrict__ out) {
    __shared__ __align__(16) char smem[51200];
    __bf16* Kt0 = (__bf16*)smem;                 // Kt[2][128*64] = 32 KB
    __bf16* Vt  = (__bf16*)(smem + 32768);       // Vt[64*128]    = 16 KB
    float*  bc  = (float*)(smem + 49152);        // [8][32] = 1 KB (+1 KB epi)

    const int t    = threadIdx.x;
    const int w8   = t >> 6;
    const int lane = t & 63;
    const int h    = lane >> 5;
    const int q32  = lane & 31;
    const int j    = w8 & 1;
    const int h4   = w8 >> 1;
    const int bh   = blockIdx.x;               // 0..31
    const int qt   = 31 - blockIdx.y;          // heavy first (LPT)
    const int qb   = 2 * qt + j;               // this wave's q-block (32 rows)
    const int C    = (2 * qt + 5) >> 2;        // 128-key chunks

    const __bf16* Qp  = Q  + (size_t)bh * S_LEN * HDIM;
    const __bf16* Kp  = Kv + (size_t)bh * S_LEN * HDIM;
    const __bf16* VTp = VT + (size_t)bh * HDIM * S_LEN;

    const int qrow = qb * 32 + q32;

    bf16x8 qreg[4];
#pragma unroll
    for (int ks = 0; ks < 4; ++ks)
        qreg[ks] = *(const bf16x8*)&Qp[(size_t)qrow * HDIM + 16 * ks + 8 * h];

    f32x16 oacc0 = ZERO16, oacc1 = ZERO16;
    float mrun = -1e30f, lrun = 0.f;

    // prologue: K chunk 0 -> buffer 0
    {
#pragma unroll
        for (int i = 0; i < 2; ++i) {
            int c16 = i * 512 + t;
            int key = c16 >> 3;
            int d0  = ((c16 & 7) ^ (key & 7)) * 8;
            gload_lds16(Kp + (size_t)key * HDIM + d0, (char*)Kt0 + c16 * 16);
        }
        __syncthreads();
    }

    for (int c = 0; c < C; ++c) {
        const int cur = c & 1;
        // issue V_c (single buffer; Vt free since last chunk's barrier 2)
        {
            const int kb = c * 128;
#pragma unroll
            for (int i = 0; i < 2; ++i) {
                int c16 = i * 512 + t;
                int d   = c16 >> 4;
                int o   = c16 & 15;
                gload_lds16(VTp + (size_t)d * S_LEN + kb + ((o ^ (d & 7)) * 8),
                            (char*)Vt + c16 * 16);
            }
        }
        // issue K_{c+1}
        if (c + 1 < C) {
            const int kb = (c + 1) * 128;
#pragma unroll
            for (int i = 0; i < 2; ++i) {
                int c16 = i * 512 + t;
                int key = c16 >> 3;
                int d0  = ((c16 & 7) ^ (key & 7)) * 8;
                gload_lds16(Kp + (size_t)(kb + key) * HDIM + d0,
                            (char*)Kt0 + (cur ^ 1) * 16384 + c16 * 16);
            }
        }

        const bool work = (4 * c + h4 <= qb);
        unsigned L[4], H[4];

        if (work) {
            const __bf16* Ktc = Kt0 + cur * 8192;
            const int klocal = 32 * h4;

            // S^T = K . Q^T
            f32x16 sac = ZERO16;
            __builtin_amdgcn_s_setprio(1);
#pragma unroll
            for (int ks = 0; ks < 4; ++ks) {
                bf16x8 kf = *(const bf16x8*)&Ktc[(klocal + q32) * 64 +
                                ((16 * ks + 8 * h) ^ ((q32 & 7) << 3))];
                sac = __builtin_amdgcn_mfma_f32_32x32x16_bf16(kf, qreg[ks], sac, 0, 0, 0);
            }
            __builtin_amdgcn_s_setprio(0);

            float rmax = sac[0];
#pragma unroll
            for (int r = 1; r < 16; ++r) rmax = fmaxf(rmax, sac[r]);
            float pmax = rmax * SM_SCALE_LOG2;
            pmax = fmaxf(pmax, __shfl_xor(pmax, 32));

            if (__any(pmax > mrun + 8.f)) {
                float mnew = fmaxf(mrun, pmax);
                float fac  = exp2f(mrun - mnew);
                mrun = mnew;
                lrun *= fac;
                bc[w8 * 32 + q32] = fac;
                asm volatile("s_waitcnt lgkmcnt(0)" ::: "memory");
                __builtin_amdgcn_sched_barrier(0);
#pragma unroll
                for (int q2 = 0; q2 < 4; ++q2) {
                    f32x4 fv = *(const f32x4*)&bc[w8 * 32 + 8 * q2 + 4 * h];
#pragma unroll
                    for (int jj = 0; jj < 4; ++jj) {
                        oacc0[4 * q2 + jj] *= fv[jj];
                        oacc1[4 * q2 + jj] *= fv[jj];
                    }
                }
            }

            float ps = 0.f;
#pragma unroll
            for (int r = 0; r < 16; ++r) {
                float pv = exp2f(__builtin_fmaf(sac[r], SM_SCALE_LOG2, -mrun));
                ps += pv;
                sac[r] = pv;
            }
            ps += __shfl_xor(ps, 32);
            lrun += ps;

#pragma unroll
            for (int g = 0; g < 4; ++g) {
                asm("v_cvt_pk_bf16_f32 %0, %1, %2"
                    : "=v"(L[g]) : "v"(sac[4 * g]), "v"(sac[4 * g + 1]));
                asm("v_cvt_pk_bf16_f32 %0, %1, %2"
                    : "=v"(H[g]) : "v"(sac[4 * g + 2]), "v"(sac[4 * g + 3]));
            }
        }

        __syncthreads();   // V_c staged & visible (drains vmcnt)

        if (work) {
            const int klocal = 32 * h4;
            __builtin_amdgcn_s_setprio(1);
#pragma unroll
            for (int s2 = 0; s2 < 2; ++s2) {
                unsigned a0 = L[2 * s2], b0 = L[2 * s2 + 1];
                unsigned a1 = H[2 * s2], b1 = H[2 * s2 + 1];
                asm("v_permlane32_swap_b32 %0, %1" : "+v"(a0), "+v"(b0));
                asm("v_permlane32_swap_b32 %0, %1" : "+v"(a1), "+v"(b1));
                unsigned wvw[4] = { a0, a1, b0, b1 };
                bf16x8 pa = *(bf16x8*)wvw;

                const int klb = klocal + 16 * s2 + 8 * h;
#pragma unroll
                for (int n = 0; n < 2; ++n) {
                    int d = 32 * n + q32;
                    bf16x8 vf = *(const bf16x8*)&Vt[d * 128 +
                                    (klb ^ ((d & 7) << 3))];
                    if (n == 0)
                        oacc0 = __builtin_amdgcn_mfma_f32_32x32x16_bf16(pa, vf, oacc0, 0, 0, 0);
                    else
                        oacc1 = __builtin_amdgcn_mfma_f32_32x32x16_bf16(pa, vf, oacc1, 0, 0, 0);
                }
            }
            __builtin_amdgcn_s_setprio(0);
        }

        __syncthreads();   // PV reads of Vt done -> next chunk may overwrite
    }

    // ---- 4-way merge: wave (j,0) <- waves (j,1..3) ----
    float* Oex = (float*)smem;                   // 6 slots x 8 KB = 48 KB
    float* MLm = (float*)(smem + 49152);         // [8][32]
    float* MLl = (float*)(smem + 50176);         // [8][32]

    if (h == 0) { MLm[w8 * 32 + q32] = mrun; MLl[w8 * 32 + q32] = lrun; }
    if (h4 != 0) {
        float* ob = Oex + (j * 3 + h4 - 1) * 2048;
#pragma unroll
        for (int q2 = 0; q2 < 4; ++q2)
#pragma unroll
            for (int jj = 0; jj < 4; ++jj) {
                int r  = 4 * q2 + jj;
                int rl = 8 * q2 + 4 * h + jj;
                ob[rl * 64 + q32]      = oacc0[r];
                ob[rl * 64 + 32 + q32] = oacc1[r];
            }
    }
    __syncthreads();

    if (h4 == 0) {
        const int b = bh >> 4, hh = bh & (NHEAD - 1);
        __bf16* op = out + (size_t)b * S_LEN * EMB + hh * HDIM;
        const float* ob1 = Oex + (j * 3 + 0) * 2048;
        const float* ob2 = Oex + (j * 3 + 1) * 2048;
        const float* ob3 = Oex + (j * 3 + 2) * 2048;
#pragma unroll
        for (int q2 = 0; q2 < 4; ++q2) {
            f32x4 mv[4], lv[4];
#pragma unroll
            for (int p = 0; p < 4; ++p) {
                int wp = (p << 1) | j;
                mv[p] = *(const f32x4*)&MLm[wp * 32 + 8 * q2 + 4 * h];
                lv[p] = *(const f32x4*)&MLl[wp * 32 + 8 * q2 + 4 * h];
            }
#pragma unroll
            for (int jj = 0; jj < 4; ++jj) {
                float mst = fmaxf(fmaxf(mv[0][jj], mv[1][jj]),
                                  fmaxf(mv[2][jj], mv[3][jj]));
                float s0 = exp2f(mv[0][jj] - mst);
                float s1 = exp2f(mv[1][jj] - mst);
                float s2 = exp2f(mv[2][jj] - mst);
                float s3 = exp2f(mv[3][jj] - mst);
                float inv = 1.f / (lv[0][jj] * s0 + lv[1][jj] * s1 +
                                   lv[2][jj] * s2 + lv[3][jj] * s3);
                int r  = 4 * q2 + jj;
                int rl = 8 * q2 + 4 * h + jj;
                int row = qb * 32 + rl;
                float v0 = (oacc0[r] * s0 + ob1[rl * 64 + q32] * s1 +
                            ob2[rl * 64 + q32] * s2 + ob3[rl * 64 + q32] * s3) * inv;
                float v1 = (oacc1[r] * s0 + ob1[rl * 64 + 32 + q32] * s1 +
                            ob2[rl * 64 + 32 + q32] * s2 + ob3[rl * 64 + 32 + q32] * s3) * inv;
                op[(size_t)row * EMB + q32]      = (__bf16)v0;
                op[(size_t)row * EMB + 32 + q32] = (__bf16)v1;
            }
        }
    }
}

// ---------------------------------------------------------------------------
extern "C" void kernel_launch(void* const* d_in, const int* in_sizes, int n_in,
                              void* d_out, int out_size, void* d_ws, size_t ws_size,
                              hipStream_t stream) {
    const float* x  = (const float*)d_in[0];
    const float* Wq = (const float*)d_in[1];
    const float* bq = (const float*)d_in[2];
    const float* Wk = (const float*)d_in[3];
    const float* bk = (const float*)d_in[4];
    const float* Wv = (const float*)d_in[5];
    const float* bv = (const float*)d_in[6];
    const float* Wo = (const float*)d_in[7];
    const float* bo = (const float*)d_in[8];
    float* out = (float*)d_out;

    char* ws = (char*)d_ws;
    __bf16* xb  = (__bf16*)(ws + 0);
    __bf16* wqb = (__bf16*)(ws + 8388608);
    __bf16* wkb = (__bf16*)(ws + 10485760);
    __bf16* wvb = (__bf16*)(ws + 12582912);
    __bf16* wob = (__bf16*)(ws + 14680064);
    __bf16* Qb  = (__bf16*)(ws + 16777216);
    __bf16* Kb  = (__bf16*)(ws + 25165824);
    __bf16* VTb = (__bf16*)(ws + 33554432);   // [B,H,HD,S] bf16
    __bf16* Ab  = (__bf16*)(ws + 41943040);

    const int M = BATCH * S_LEN;  // 4096
    const int N = EMB;            // 1024
    const int K = EMB;            // 1024

    f2b_all<<<8192, 256, 0, stream>>>(x, Wq, Wk, Wv, Wo, xb, wqb, wkb, wvb, wob);

    gemm_qkv<<<dim3(24, 32), 256, 0, stream>>>(
        xb, wqb, wkb, wvb, bq, bk, bv, Qb, Kb, VTb, K);

    attn7_kernel<<<dim3(BATCH * NHEAD, 32), 512, 0, stream>>>(Qb, Kb, VTb, Ab);

    gemm_o64<<<dim3(16, M / 128), 256, 0, stream>>>(Ab, wob, bo, out, M, N, K);
}